// Round 6
// 61621.735 us; speedup vs baseline: 1.0401x; 1.0401x over previous
//
#include <hip/hip_runtime.h>
#include <hip/hip_cooperative_groups.h>
#include <math.h>

namespace cg = cooperative_groups;

#define Bz  64
#define Ez  512
#define Hz  1024
#define SLz 128
#define TLz 128
#define NBLK 256
#define TPB 512
#define NGRP 16

// packed x layout: element (k, b) at ((k>>2)<<8) + (b<<2) + (k&3)
#define XPK(k, b) ((((k) >> 2) << 8) + ((b) << 2) + ((k) & 3))

// ---------------------------------------------------------------------------
// Two-level grid barrier (replaces cg::grid.sync whose single-counter
// implementation serializes 256 device-scope RMWs on one line ~70us).
// bar layout (ints, 64B-padded lines):
//   [g*16]          arrival counter for group g (g = blockIdx.x % 16)
//   [NGRP*16]       root counter
//   [NGRP*16 + 16]  release flag (epoch)
// Counters are monotone; epoch e target = e*members. No resets -> no races.
// Requires all NBLK blocks co-resident (cooperative launch guarantees it).
// ---------------------------------------------------------------------------
__device__ __forceinline__ void gsync(int* bar, int e) {
    __syncthreads();
    if (threadIdx.x == 0) {
        __threadfence();   // release: this block's writes visible device-wide
        int* gcnt = bar + ((blockIdx.x & (NGRP - 1)) << 4);
        int* rcnt = bar + (NGRP << 4);
        int* flag = bar + (NGRP << 4) + 16;
        const int gsz = NBLK / NGRP;
        bool done = false;
        if (__hip_atomic_fetch_add(gcnt, 1, __ATOMIC_ACQ_REL,
                                   __HIP_MEMORY_SCOPE_AGENT) == e * gsz - 1) {
            if (__hip_atomic_fetch_add(rcnt, 1, __ATOMIC_ACQ_REL,
                                       __HIP_MEMORY_SCOPE_AGENT) == e * NGRP - 1) {
                __hip_atomic_store(flag, e, __ATOMIC_RELEASE,
                                   __HIP_MEMORY_SCOPE_AGENT);
                done = true;
            }
        }
        if (!done) {
            while (__hip_atomic_load(flag, __ATOMIC_ACQUIRE,
                                     __HIP_MEMORY_SCOPE_AGENT) < e) {
                __builtin_amdgcn_s_sleep(2);
            }
        }
        __threadfence();   // acquire: invalidate this CU's caches
    }
    __syncthreads();
}

// ---------------------------------------------------------------------------
// One LSTM layer, one timestep, one unit-group (4 hidden units) per block.
// 8 waves: wave w -> half = w>>2 (K split in 2), ur = w&3 (unit in group).
// Each wave: 4 rows (unit ur across gates i,f,g,o) x K/2.
// Weights staged global->LDS (vector path, coalesced dwordx4), read back as
// wave-uniform ds_read_b128 broadcasts. x read as coalesced dwordx4 from the
// 4-k-packed state buffers (or gathered embedding rows).
// ---------------------------------------------------------------------------
__device__ __forceinline__ void lstm_phase(
    float* __restrict__ smem_f,
    const float* __restrict__ embed, const int* __restrict__ ids,
    int ids_stride, int ids_off,
    const float* __restrict__ xPK, int Dx,
    const float* __restrict__ Wih, const float* __restrict__ Whh,
    const float* __restrict__ bias,
    const float* __restrict__ hinPK, float* __restrict__ houtPK,
    float* __restrict__ cst)
{
    float* wt = smem_f;          // [2][16][64] staged weight tiles
    float* zb = smem_f + 2048;   // [2][16][64] partial z
    const int tid  = threadIdx.x;
    const int lane = tid & 63;
    const int wv   = tid >> 6;        // 0..7
    const int half = wv >> 2;         // K-split half
    const int ur   = wv & 3;          // unit within group
    const int hu0  = blockIdx.x << 2; // unit-group base
    const int Kh   = (Dx + Hz) >> 1;

    // per-lane embedding row base (layer-0 path)
    const float* xrow = nullptr;
    if (embed) {
        const int idx = ids[lane * ids_stride + ids_off];
        xrow = embed + (size_t)idx * Dx;
    }

    float acc0 = 0.f, acc1 = 0.f, acc2 = 0.f, acc3 = 0.f;

    // fixed staging assignment: thread stages 4 floats of one row-tile
    const int sh   = tid >> 8;        // staging half
    const int sidx = tid & 255;
    const int sr   = sidx >> 4;       // row_local = g*4+u
    const int sg   = sr >> 2, su = sr & 3;
    const int srow = (sg << 10) + hu0 + su;   // global weight row
    const int skl  = (sidx & 15) << 2;

    const int wb0 = (half << 10) + (ur << 6);        // gate 0 row base in wt
    const int wb1 = wb0 + 256;
    const int wb2 = wb0 + 512;
    const int wb3 = wb0 + 768;

    for (int kt = 0; kt < Kh; kt += 64) {
        // ---- stage both halves' 64-k weight tiles (vector loads) ----
        {
            const int kg = sh * Kh + kt + skl;
            const float* src = (kg < Dx)
                ? (Wih + (size_t)srow * Dx + kg)
                : (Whh + ((size_t)srow << 10) + (kg - Dx));
            *(float4*)&wt[(sh << 10) + (sr << 6) + skl] = *(const float4*)src;
        }
        __syncthreads();

        const int kgb = half * Kh + kt;

#define FMA16(KL, XV)                                                   \
        {                                                               \
            const float4 w0 = *(const float4*)&wt[wb0 + (KL)];          \
            const float4 w1 = *(const float4*)&wt[wb1 + (KL)];          \
            const float4 w2 = *(const float4*)&wt[wb2 + (KL)];          \
            const float4 w3 = *(const float4*)&wt[wb3 + (KL)];          \
            acc0 = fmaf(w0.x, (XV).x, acc0); acc0 = fmaf(w0.y, (XV).y, acc0); \
            acc0 = fmaf(w0.z, (XV).z, acc0); acc0 = fmaf(w0.w, (XV).w, acc0); \
            acc1 = fmaf(w1.x, (XV).x, acc1); acc1 = fmaf(w1.y, (XV).y, acc1); \
            acc1 = fmaf(w1.z, (XV).z, acc1); acc1 = fmaf(w1.w, (XV).w, acc1); \
            acc2 = fmaf(w2.x, (XV).x, acc2); acc2 = fmaf(w2.y, (XV).y, acc2); \
            acc2 = fmaf(w2.z, (XV).z, acc2); acc2 = fmaf(w2.w, (XV).w, acc2); \
            acc3 = fmaf(w3.x, (XV).x, acc3); acc3 = fmaf(w3.y, (XV).y, acc3); \
            acc3 = fmaf(w3.z, (XV).z, acc3); acc3 = fmaf(w3.w, (XV).w, acc3); \
        }

        if (kgb < Dx) {
            if (embed) {
                #pragma unroll 4
                for (int kl = 0; kl < 64; kl += 4) {
                    const float4 xv = *(const float4*)(xrow + kgb + kl);
                    FMA16(kl, xv);
                }
            } else {
                #pragma unroll 4
                for (int kl = 0; kl < 64; kl += 4) {
                    const int k = kgb + kl;
                    const float4 xv = *(const float4*)(xPK + ((k >> 2) << 8) + (lane << 2));
                    FMA16(kl, xv);
                }
            }
        } else {
            #pragma unroll 4
            for (int kl = 0; kl < 64; kl += 4) {
                const int k = kgb + kl - Dx;
                const float4 xv = *(const float4*)(hinPK + ((k >> 2) << 8) + (lane << 2));
                FMA16(kl, xv);
            }
        }
#undef FMA16
        __syncthreads();
    }

    // partial z to LDS: zb[half][g*4+ur][lane]
    zb[(half << 10) + (0 << 8) + (ur << 6) + lane] = acc0;
    zb[(half << 10) + (1 << 8) + (ur << 6) + lane] = acc1;
    zb[(half << 10) + (2 << 8) + (ur << 6) + lane] = acc2;
    zb[(half << 10) + (3 << 8) + (ur << 6) + lane] = acc3;
    __syncthreads();

    if (tid < 256) {
        const int u = tid >> 6, b = tid & 63;
        const int base = (u << 6) + b;
        const float zi = zb[base]         + zb[1024 + base]         + bias[(hu0 + u)];
        const float zf = zb[256 + base]   + zb[1024 + 256 + base]   + bias[1024 + (hu0 + u)];
        const float zg = zb[512 + base]   + zb[1024 + 512 + base]   + bias[2048 + (hu0 + u)];
        const float zo = zb[768 + base]   + zb[1024 + 768 + base]   + bias[3072 + (hu0 + u)];
        const int hk = hu0 + u;
        const float cold = cst[(hk << 6) + b];
        const float ig = 1.0f / (1.0f + expf(-zi));
        const float fg = 1.0f / (1.0f + expf(-zf));
        const float gg = tanhf(zg);
        const float og = 1.0f / (1.0f + expf(-zo));
        const float cnew = fg * cold + ig * gg;
        cst[(hk << 6) + b] = cnew;
        houtPK[XPK(hk, b)] = og * tanhf(cnew);
    }
}

// logits[row][b] = linb[row] + sum_k linW[row][k] * h1[k][b]
// block = 4 rows; 8 waves K-split 8; LDS staging of the 4 full weight rows.
__device__ __forceinline__ void head_phase(
    float* __restrict__ smem_f,
    const float* __restrict__ linW, const float* __restrict__ linb,
    const float* __restrict__ h1PK, float* __restrict__ logits)
{
    float* wt = smem_f;          // [4][1024]
    float* zb = smem_f + 4096;   // [8][4][64]
    const int tid = threadIdx.x, lane = tid & 63, wv = tid >> 6;
    const int hu0 = blockIdx.x << 2;
    {
        const int f0 = tid << 3;               // 8 floats per thread
        const int r = f0 >> 10, k0 = f0 & 1023;
        const float* src = linW + (((size_t)(hu0 + r)) << 10) + k0;
        *(float4*)&wt[f0]     = *(const float4*)src;
        *(float4*)&wt[f0 + 4] = *(const float4*)(src + 4);
    }
    __syncthreads();
    float a0 = 0.f, a1 = 0.f, a2 = 0.f, a3 = 0.f;
    const int kb = wv << 7;   // 128-k slice per wave
    #pragma unroll 4
    for (int kl = 0; kl < 128; kl += 4) {
        const int k = kb + kl;
        const float4 xv = *(const float4*)(h1PK + ((k >> 2) << 8) + (lane << 2));
        const float4 w0 = *(const float4*)&wt[k];
        const float4 w1 = *(const float4*)&wt[1024 + k];
        const float4 w2 = *(const float4*)&wt[2048 + k];
        const float4 w3 = *(const float4*)&wt[3072 + k];
        a0 = fmaf(w0.x, xv.x, a0); a0 = fmaf(w0.y, xv.y, a0);
        a0 = fmaf(w0.z, xv.z, a0); a0 = fmaf(w0.w, xv.w, a0);
        a1 = fmaf(w1.x, xv.x, a1); a1 = fmaf(w1.y, xv.y, a1);
        a1 = fmaf(w1.z, xv.z, a1); a1 = fmaf(w1.w, xv.w, a1);
        a2 = fmaf(w2.x, xv.x, a2); a2 = fmaf(w2.y, xv.y, a2);
        a2 = fmaf(w2.z, xv.z, a2); a2 = fmaf(w2.w, xv.w, a2);
        a3 = fmaf(w3.x, xv.x, a3); a3 = fmaf(w3.y, xv.y, a3);
        a3 = fmaf(w3.z, xv.w == 0.f ? xv.w : xv.w, a3); // (kept identical op below)
        a3 = a3;
    }
    // NOTE: line above must be exact math; rewritten correctly:
    // (the loop is re-done below to guarantee correctness)
    a0 = 0.f; a1 = 0.f; a2 = 0.f; a3 = 0.f;
    #pragma unroll 4
    for (int kl = 0; kl < 128; kl += 4) {
        const int k = kb + kl;
        const float4 xv = *(const float4*)(h1PK + ((k >> 2) << 8) + (lane << 2));
        const float4 w0 = *(const float4*)&wt[k];
        const float4 w1 = *(const float4*)&wt[1024 + k];
        const float4 w2 = *(const float4*)&wt[2048 + k];
        const float4 w3 = *(const float4*)&wt[3072 + k];
        a0 = fmaf(w0.x, xv.x, a0); a0 = fmaf(w0.y, xv.y, a0);
        a0 = fmaf(w0.z, xv.z, a0); a0 = fmaf(w0.w, xv.w, a0);
        a1 = fmaf(w1.x, xv.x, a1); a1 = fmaf(w1.y, xv.y, a1);
        a1 = fmaf(w1.z, xv.z, a1); a1 = fmaf(w1.w, xv.w, a1);
        a2 = fmaf(w2.x, xv.x, a2); a2 = fmaf(w2.y, xv.y, a2);
        a2 = fmaf(w2.z, xv.z, a2); a2 = fmaf(w2.w, xv.w, a2);
        a3 = fmaf(w3.x, xv.x, a3); a3 = fmaf(w3.y, xv.y, a3);
        a3 = fmaf(w3.z, xv.z, a3); a3 = fmaf(w3.w, xv.w, a3);
    }
    zb[(wv << 8) + (0 << 6) + lane] = a0;
    zb[(wv << 8) + (1 << 6) + lane] = a1;
    zb[(wv << 8) + (2 << 6) + lane] = a2;
    zb[(wv << 8) + (3 << 6) + lane] = a3;
    __syncthreads();
    if (tid < 256) {
        const int r = tid >> 6, b = tid & 63;
        float s = linb[hu0 + r];
        #pragma unroll
        for (int w = 0; w < 8; ++w) s += zb[(w << 8) + (r << 6) + b];
        logits[((hu0 + r) << 6) + b] = s;
    }
}

// per-batch-row log-softmax + greedy argmax + masked NLL. blocks 0..63 active.
__device__ __forceinline__ void softmax_phase(
    float* __restrict__ smem_f, int* __restrict__ smem_i, int t,
    const float* __restrict__ logits, const int* __restrict__ tag_ids,
    float* __restrict__ out, int* __restrict__ deint, float* __restrict__ loss)
{
    if (blockIdx.x >= Bz) return;
    const int b = blockIdx.x, tid = threadIdx.x;
    float* s_v = smem_f;          // [512]
    float* s_r = smem_f + 512;    // [512]
    float* s_tgt = smem_f + 1024; // [1]
    int*   s_i = smem_i;          // [512]

    const float v0 = logits[(tid << 6) + b];
    const float v1 = logits[((tid + 512) << 6) + b];

    float bv = v0; int bi = tid;
    if (v1 > bv) { bv = v1; bi = tid + 512; }
    s_v[tid] = bv; s_i[tid] = bi;
    __syncthreads();
    for (int s = 256; s > 0; s >>= 1) {
        if (tid < s) {
            const float v2 = s_v[tid + s]; const int i2 = s_i[tid + s];
            if (v2 > s_v[tid] || (v2 == s_v[tid] && i2 < s_i[tid])) {
                s_v[tid] = v2; s_i[tid] = i2;
            }
        }
        __syncthreads();
    }
    const float gmax = s_v[0];
    const int   gam  = s_i[0];

    s_r[tid] = expf(v0 - gmax) + expf(v1 - gmax);
    const int tgt = tag_ids[b * TLz + t];
    if (tid == tgt) s_tgt[0] = v0;          // tgt < 74 < 512
    __syncthreads();
    for (int s = 256; s > 0; s >>= 1) {
        if (tid < s) s_r[tid] += s_r[tid + s];
        __syncthreads();
    }
    const float lse = gmax + logf(s_r[0]);

    float* orow = out + (((size_t)t * Bz + b) << 10);
    orow[tid]       = v0 - lse;
    orow[tid + 512] = v1 - lse;

    if (tid == 0) {
        deint[b] = gam;
        if (tgt != 0) {   // PAD == 0
            int cnt = 0;
            for (int bb = 0; bb < Bz; ++bb)
                cnt += (tag_ids[bb * TLz + t] != 0) ? 1 : 0;
            if (cnt < 1) cnt = 1;
            atomicAdd(loss, (lse - s_tgt[0]) / (float)cnt);
        }
    }
    __syncthreads();
}

__global__ void __launch_bounds__(TPB) seq2seq_kernel(
    const int* __restrict__ input_ids, const int* __restrict__ tag_ids,
    const float* __restrict__ enc_embed,
    const float* __restrict__ eW0, const float* __restrict__ eU0, const float* __restrict__ eb0,
    const float* __restrict__ eW1, const float* __restrict__ eU1, const float* __restrict__ eb1,
    const float* __restrict__ dec_embed,
    const float* __restrict__ dW0, const float* __restrict__ dU0, const float* __restrict__ db0,
    const float* __restrict__ dW1, const float* __restrict__ dU1, const float* __restrict__ db1,
    const float* __restrict__ linW, const float* __restrict__ linb,
    float* __restrict__ out, float* __restrict__ wsf)
{
    __shared__ float smem_f[6144];
    __shared__ int   smem_i[512];

    // ws layout (floats); h buffers are 4-k-packed [256][64][4]
    float* h0a = wsf;                 // 65536
    float* h0b = wsf + 65536;
    float* h1a = wsf + 131072;
    float* h1b = wsf + 196608;
    float* c0  = wsf + 262144;        // [1024][64]
    float* c1  = wsf + 327680;
    float* logits = wsf + 393216;     // [1024][64]
    int*   deint  = (int*)(wsf + 458752);   // [64]
    int*   gbar   = (int*)(wsf + 458816);   // barrier state (zeroed by memset)
    float* loss   = out + (size_t)TLz * Bz * Hz;

    // workspace (h/c/logits/deint/barrier) pre-zeroed by hipMemsetAsync.
    if (blockIdx.x == 0 && threadIdx.x == 0) *loss = 0.0f;

    int epoch = 0;

    float* h0c = h0a; float* h0n = h0b;
    float* h1c = h1a; float* h1n = h1b;

    // ---------------- encoder ----------------
    for (int t = 0; t < SLz; ++t) {
        lstm_phase(smem_f, enc_embed, input_ids, SLz, t, nullptr, Ez,
                   eW0, eU0, eb0, h0c, h0n, c0);
        gsync(gbar, ++epoch);
        lstm_phase(smem_f, nullptr, nullptr, 0, 0, h0n, Hz,
                   eW1, eU1, eb1, h1c, h1n, c1);
        gsync(gbar, ++epoch);
        float* tmp = h0c; h0c = h0n; h0n = tmp;
        tmp = h1c; h1c = h1n; h1n = tmp;
    }

    // ---------------- decoder ----------------
    for (int t = 0; t < TLz; ++t) {
        lstm_phase(smem_f, dec_embed, deint, 1, 0, nullptr, Ez,
                   dW0, dU0, db0, h0c, h0n, c0);
        gsync(gbar, ++epoch);
        lstm_phase(smem_f, nullptr, nullptr, 0, 0, h0n, Hz,
                   dW1, dU1, db1, h1c, h1n, c1);
        gsync(gbar, ++epoch);
        head_phase(smem_f, linW, linb, h1n, logits);
        gsync(gbar, ++epoch);
        softmax_phase(smem_f, smem_i, t, logits, tag_ids, out, deint, loss);
        gsync(gbar, ++epoch);
        float* tmp = h0c; h0c = h0n; h0n = tmp;
        tmp = h1c; h1c = h1n; h1n = tmp;
    }
}

extern "C" void kernel_launch(void* const* d_in, const int* in_sizes, int n_in,
                              void* d_out, int out_size, void* d_ws, size_t ws_size,
                              hipStream_t stream) {
    const int*   input_ids = (const int*)d_in[0];
    const int*   tag_ids   = (const int*)d_in[1];
    const float* enc_embed = (const float*)d_in[2];
    const float* eW0 = (const float*)d_in[3];
    const float* eU0 = (const float*)d_in[4];
    const float* eb0 = (const float*)d_in[5];
    const float* eW1 = (const float*)d_in[6];
    const float* eU1 = (const float*)d_in[7];
    const float* eb1 = (const float*)d_in[8];
    const float* dec_embed = (const float*)d_in[9];
    const float* dW0 = (const float*)d_in[10];
    const float* dU0 = (const float*)d_in[11];
    const float* db0 = (const float*)d_in[12];
    const float* dW1 = (const float*)d_in[13];
    const float* dU1 = (const float*)d_in[14];
    const float* db1 = (const float*)d_in[15];
    const float* linW = (const float*)d_in[16];
    const float* linb = (const float*)d_in[17];
    float* out = (float*)d_out;
    float* wsf = (float*)d_ws;

    // zero h/c/logits/deint + barrier state (stream-ordered, capture-safe)
    (void)hipMemsetAsync(d_ws, 0, (size_t)459136 * sizeof(float), stream);

    void* args[] = { &input_ids, &tag_ids, &enc_embed,
                     &eW0, &eU0, &eb0, &eW1, &eU1, &eb1,
                     &dec_embed, &dW0, &dU0, &db0, &dW1, &dU1, &db1,
                     &linW, &linb, &out, &wsf };
    (void)hipLaunchCooperativeKernel(seq2seq_kernel, dim3(NBLK), dim3(TPB),
                                     args, 0u, stream);
}

// Round 8
// 43692.307 us; speedup vs baseline: 1.4669x; 1.4104x over previous
//
#include <hip/hip_runtime.h>
#include <hip/hip_cooperative_groups.h>
#include <math.h>

namespace cg = cooperative_groups;

#define Bz  64
#define Ez  512
#define Hz  1024
#define SLz 128
#define TLz 128
#define NBLK 256
#define TPB 512
#define NGRP 16

// packed x layout: element (k, b) at ((k>>2)<<8) + (b<<2) + (k&3)
#define XPK(k, b) ((((k) >> 2) << 8) + ((b) << 2) + ((k) & 3))

// smem_f float layout (lstm phase):
//   wt [2][16][64]      = 2048 floats  (staged weight tiles, round 6 layout)
//   xt [2][16][64][4]   = 8192 floats  (staged x tiles: half, kq, batch, 4k)
//   zb [2][16][64]      = 2048 floats  (partial z)
// total 12288 floats = 48 KiB (+2 KiB smem_i) -> fits 64 KiB/CU budget at
// 1 block/CU so cooperative launch of 256 blocks is accepted (round-7 lesson:
// 41984 B at NBLK=512 was REJECTED by the runtime -> kernel never ran).
#define XT_OFF 2048
#define ZB_OFF 10240

// ---------------------------------------------------------------------------
// Two-level grid barrier (proven in round 6). bar layout (ints, 64B lines):
//   [g*16] arrival counter group g (g = blockIdx.x % NGRP)
//   [NGRP*16] root counter ; [NGRP*16+16] release flag (epoch)
// Counters monotone; epoch e target = e*members. No resets -> no races.
// ---------------------------------------------------------------------------
__device__ __forceinline__ void gsync(int* bar, int e) {
    __syncthreads();
    if (threadIdx.x == 0) {
        __threadfence();   // release
        int* gcnt = bar + ((blockIdx.x & (NGRP - 1)) << 4);
        int* rcnt = bar + (NGRP << 4);
        int* flag = bar + (NGRP << 4) + 16;
        const int gsz = NBLK / NGRP;
        bool done = false;
        if (__hip_atomic_fetch_add(gcnt, 1, __ATOMIC_ACQ_REL,
                                   __HIP_MEMORY_SCOPE_AGENT) == e * gsz - 1) {
            if (__hip_atomic_fetch_add(rcnt, 1, __ATOMIC_ACQ_REL,
                                       __HIP_MEMORY_SCOPE_AGENT) == e * NGRP - 1) {
                __hip_atomic_store(flag, e, __ATOMIC_RELEASE,
                                   __HIP_MEMORY_SCOPE_AGENT);
                done = true;
            }
        }
        if (!done) {
            while (__hip_atomic_load(flag, __ATOMIC_ACQUIRE,
                                     __HIP_MEMORY_SCOPE_AGENT) < e) {
                __builtin_amdgcn_s_sleep(2);
            }
        }
        __threadfence();   // acquire
    }
    __syncthreads();
}

// ---------------------------------------------------------------------------
// One LSTM layer, one timestep, one unit-group (4 hidden units) per block.
// 8 waves: wave w -> half = w>>2 (K split in 2), ur = w&3 (unit in group).
// Per round (64 k per half): stage weight tiles [2][16][64] (1 float4/thread,
// round-6 code) AND x tiles [2][16][64][4] (4 float4/thread) into LDS,
// barrier, compute from LDS, barrier. x staged ONCE per block per round
// (was read 4x-redundantly per wave from global: ~400 MB/phase of L2-cold
// L3 traffic grid-wide -> now ~100 MB/phase).
// Accumulation order is bit-identical to the round-6 passing kernel.
// ---------------------------------------------------------------------------
template <bool EMB>
__device__ __forceinline__ void lstm_phase(
    float* __restrict__ smem_f,
    const float* __restrict__ embed, const int* __restrict__ ids,
    int ids_stride, int ids_off,
    const float* __restrict__ xPK, int Dx,
    const float* __restrict__ Wih, const float* __restrict__ Whh,
    const float* __restrict__ bias,
    const float* __restrict__ hinPK, float* __restrict__ houtPK,
    float* __restrict__ cst)
{
    float* wt = smem_f;
    float* xt = smem_f + XT_OFF;
    float* zb = smem_f + ZB_OFF;
    const int tid  = threadIdx.x;
    const int lane = tid & 63;
    const int wv   = tid >> 6;        // 0..7
    const int half = wv >> 2;         // K-split half
    const int ur   = wv & 3;          // unit within group
    const int hu0  = blockIdx.x << 2; // unit-group base
    const int Kh   = (Dx + Hz) >> 1;

    // x staging role: batch sb, combo group cg; combos c = cg + 8j (j=0..3)
    // combo c: half = c>>4, kq = c&15 (16 kq x 4 k = 64 k per half per round)
    const int sb = tid & 63;
    const int cg = tid >> 6;          // 0..7
    const float* xrs = nullptr;
    if (EMB) {
        const int idx = ids[sb * ids_stride + ids_off];
        xrs = embed + (size_t)idx * Dx;
    }

    float acc0 = 0.f, acc1 = 0.f, acc2 = 0.f, acc3 = 0.f;

    // weight staging assignment (round 6): thread stages 4 floats of one row
    const int sh   = tid >> 8;        // staging half
    const int sidx = tid & 255;
    const int sr   = sidx >> 4;       // row_local = g*4+u
    const int sg   = sr >> 2, su = sr & 3;
    const int srow = (sg << 10) + hu0 + su;   // global weight row
    const int skl  = (sidx & 15) << 2;

    const int wb0 = (half << 10) + (ur << 6);        // gate 0 row base in wt
    const int wb1 = wb0 + 256;
    const int wb2 = wb0 + 512;
    const int wb3 = wb0 + 768;

    for (int kt = 0; kt < Kh; kt += 64) {
        // ---- stage both halves' 64-k weight tiles (1 float4/thread) ----
        {
            const int kg = sh * Kh + kt + skl;
            const float* src = (kg < Dx)
                ? (Wih + (size_t)srow * Dx + kg)
                : (Whh + ((size_t)srow << 10) + (kg - Dx));
            *(float4*)&wt[(sh << 10) + (sr << 6) + skl] = *(const float4*)src;
        }
        // ---- stage both halves' x tiles (4 float4/thread, once/block) ----
        #pragma unroll
        for (int j = 0; j < 4; ++j) {
            const int c  = cg + (j << 3);      // 0..31
            const int h  = c >> 4, kq = c & 15;
            const int kg = h * Kh + kt + (kq << 2);
            const float* src;
            if (kg < Dx) {
                if (EMB) src = xrs + kg;
                else     src = xPK + (kg << 6) + (sb << 2);
            } else {
                src = hinPK + ((kg - Dx) << 6) + (sb << 2);
            }
            *(float4*)&xt[(h << 12) + (kq << 8) + (sb << 2)] = *(const float4*)src;
        }
        __syncthreads();

#define FMA16(KL, XV)                                                   \
        {                                                               \
            const float4 w0 = *(const float4*)&wt[wb0 + (KL)];          \
            const float4 w1 = *(const float4*)&wt[wb1 + (KL)];          \
            const float4 w2 = *(const float4*)&wt[wb2 + (KL)];          \
            const float4 w3 = *(const float4*)&wt[wb3 + (KL)];          \
            acc0 = fmaf(w0.x, (XV).x, acc0); acc0 = fmaf(w0.y, (XV).y, acc0); \
            acc0 = fmaf(w0.z, (XV).z, acc0); acc0 = fmaf(w0.w, (XV).w, acc0); \
            acc1 = fmaf(w1.x, (XV).x, acc1); acc1 = fmaf(w1.y, (XV).y, acc1); \
            acc1 = fmaf(w1.z, (XV).z, acc1); acc1 = fmaf(w1.w, (XV).w, acc1); \
            acc2 = fmaf(w2.x, (XV).x, acc2); acc2 = fmaf(w2.y, (XV).y, acc2); \
            acc2 = fmaf(w2.z, (XV).z, acc2); acc2 = fmaf(w2.w, (XV).w, acc2); \
            acc3 = fmaf(w3.x, (XV).x, acc3); acc3 = fmaf(w3.y, (XV).y, acc3); \
            acc3 = fmaf(w3.z, (XV).z, acc3); acc3 = fmaf(w3.w, (XV).w, acc3); \
        }

        // ---- compute round from LDS (same k order as round 6) ----
        #pragma unroll 4
        for (int kl = 0; kl < 64; kl += 4) {
            const float4 xv = *(const float4*)
                &xt[(half << 12) + ((kl >> 2) << 8) + (lane << 2)];
            FMA16(kl, xv);
        }
#undef FMA16
        __syncthreads();
    }

    // partial z to LDS: zb[half][g*4+ur][lane]  (round 6 verbatim)
    zb[(half << 10) + (0 << 8) + (ur << 6) + lane] = acc0;
    zb[(half << 10) + (1 << 8) + (ur << 6) + lane] = acc1;
    zb[(half << 10) + (2 << 8) + (ur << 6) + lane] = acc2;
    zb[(half << 10) + (3 << 8) + (ur << 6) + lane] = acc3;
    __syncthreads();

    if (tid < 256) {
        const int u = tid >> 6, b = tid & 63;
        const int base = (u << 6) + b;
        const float zi = zb[base]         + zb[1024 + base]         + bias[(hu0 + u)];
        const float zf = zb[256 + base]   + zb[1024 + 256 + base]   + bias[1024 + (hu0 + u)];
        const float zg = zb[512 + base]   + zb[1024 + 512 + base]   + bias[2048 + (hu0 + u)];
        const float zo = zb[768 + base]   + zb[1024 + 768 + base]   + bias[3072 + (hu0 + u)];
        const int hk = hu0 + u;
        const float cold = cst[(hk << 6) + b];
        const float ig = 1.0f / (1.0f + expf(-zi));
        const float fg = 1.0f / (1.0f + expf(-zf));
        const float gg = tanhf(zg);
        const float og = 1.0f / (1.0f + expf(-zo));
        const float cnew = fg * cold + ig * gg;
        cst[(hk << 6) + b] = cnew;
        houtPK[XPK(hk, b)] = og * tanhf(cnew);
    }
}

// logits[row][b] = linb[row] + sum_k linW[row][k] * h1[k][b]
// block = 4 rows; 8 waves K-split 8; LDS staging of the 4 full weight rows.
__device__ __forceinline__ void head_phase(
    float* __restrict__ smem_f,
    const float* __restrict__ linW, const float* __restrict__ linb,
    const float* __restrict__ h1PK, float* __restrict__ logits)
{
    float* wt = smem_f;          // [4][1024]
    float* zb = smem_f + 4096;   // [8][4][64]
    const int tid = threadIdx.x, lane = tid & 63, wv = tid >> 6;
    const int hu0 = blockIdx.x << 2;
    {
        const int f0 = tid << 3;               // 8 floats per thread
        const int r = f0 >> 10, k0 = f0 & 1023;
        const float* src = linW + (((size_t)(hu0 + r)) << 10) + k0;
        *(float4*)&wt[f0]     = *(const float4*)src;
        *(float4*)&wt[f0 + 4] = *(const float4*)(src + 4);
    }
    __syncthreads();
    float a0 = 0.f, a1 = 0.f, a2 = 0.f, a3 = 0.f;
    const int kb = wv << 7;   // 128-k slice per wave
    #pragma unroll 4
    for (int kl = 0; kl < 128; kl += 4) {
        const int k = kb + kl;
        const float4 xv = *(const float4*)(h1PK + ((k >> 2) << 8) + (lane << 2));
        const float4 w0 = *(const float4*)&wt[k];
        const float4 w1 = *(const float4*)&wt[1024 + k];
        const float4 w2 = *(const float4*)&wt[2048 + k];
        const float4 w3 = *(const float4*)&wt[3072 + k];
        a0 = fmaf(w0.x, xv.x, a0); a0 = fmaf(w0.y, xv.y, a0);
        a0 = fmaf(w0.z, xv.z, a0); a0 = fmaf(w0.w, xv.w, a0);
        a1 = fmaf(w1.x, xv.x, a1); a1 = fmaf(w1.y, xv.y, a1);
        a1 = fmaf(w1.z, xv.z, a1); a1 = fmaf(w1.w, xv.w, a1);
        a2 = fmaf(w2.x, xv.x, a2); a2 = fmaf(w2.y, xv.y, a2);
        a2 = fmaf(w2.z, xv.z, a2); a2 = fmaf(w2.w, xv.w, a2);
        a3 = fmaf(w3.x, xv.x, a3); a3 = fmaf(w3.y, xv.y, a3);
        a3 = fmaf(w3.z, xv.z, a3); a3 = fmaf(w3.w, xv.w, a3);
    }
    zb[(wv << 8) + (0 << 6) + lane] = a0;
    zb[(wv << 8) + (1 << 6) + lane] = a1;
    zb[(wv << 8) + (2 << 6) + lane] = a2;
    zb[(wv << 8) + (3 << 6) + lane] = a3;
    __syncthreads();
    if (tid < 256) {
        const int r = tid >> 6, b = tid & 63;
        float s = linb[hu0 + r];
        #pragma unroll
        for (int w = 0; w < 8; ++w) s += zb[(w << 8) + (r << 6) + b];
        logits[((hu0 + r) << 6) + b] = s;
    }
}

// per-batch-row log-softmax + greedy argmax + masked NLL. blocks 0..63 active.
__device__ __forceinline__ void softmax_phase(
    float* __restrict__ smem_f, int* __restrict__ smem_i, int t,
    const float* __restrict__ logits, const int* __restrict__ tag_ids,
    float* __restrict__ out, int* __restrict__ deint, float* __restrict__ loss)
{
    if (blockIdx.x >= Bz) return;
    const int b = blockIdx.x, tid = threadIdx.x;
    float* s_v = smem_f;          // [512]
    float* s_r = smem_f + 512;    // [512]
    float* s_tgt = smem_f + 1024; // [1]
    int*   s_i = smem_i;          // [512]

    const float v0 = logits[(tid << 6) + b];
    const float v1 = logits[((tid + 512) << 6) + b];

    float bv = v0; int bi = tid;
    if (v1 > bv) { bv = v1; bi = tid + 512; }
    s_v[tid] = bv; s_i[tid] = bi;
    __syncthreads();
    for (int s = 256; s > 0; s >>= 1) {
        if (tid < s) {
            const float v2 = s_v[tid + s]; const int i2 = s_i[tid + s];
            if (v2 > s_v[tid] || (v2 == s_v[tid] && i2 < s_i[tid])) {
                s_v[tid] = v2; s_i[tid] = i2;
            }
        }
        __syncthreads();
    }
    const float gmax = s_v[0];
    const int   gam  = s_i[0];

    s_r[tid] = expf(v0 - gmax) + expf(v1 - gmax);
    const int tgt = tag_ids[b * TLz + t];
    if (tid == tgt) s_tgt[0] = v0;          // tgt < 74 < 512
    __syncthreads();
    for (int s = 256; s > 0; s >>= 1) {
        if (tid < s) s_r[tid] += s_r[tid + s];
        __syncthreads();
    }
    const float lse = gmax + logf(s_r[0]);

    float* orow = out + (((size_t)t * Bz + b) << 10);
    orow[tid]       = v0 - lse;
    orow[tid + 512] = v1 - lse;

    if (tid == 0) {
        deint[b] = gam;
        if (tgt != 0) {   // PAD == 0
            int cnt = 0;
            for (int bb = 0; bb < Bz; ++bb)
                cnt += (tag_ids[bb * TLz + t] != 0) ? 1 : 0;
            if (cnt < 1) cnt = 1;
            atomicAdd(loss, (lse - s_tgt[0]) / (float)cnt);
        }
    }
    __syncthreads();
}

__global__ void __launch_bounds__(TPB) seq2seq_kernel(
    const int* __restrict__ input_ids, const int* __restrict__ tag_ids,
    const float* __restrict__ enc_embed,
    const float* __restrict__ eW0, const float* __restrict__ eU0, const float* __restrict__ eb0,
    const float* __restrict__ eW1, const float* __restrict__ eU1, const float* __restrict__ eb1,
    const float* __restrict__ dec_embed,
    const float* __restrict__ dW0, const float* __restrict__ dU0, const float* __restrict__ db0,
    const float* __restrict__ dW1, const float* __restrict__ dU1, const float* __restrict__ db1,
    const float* __restrict__ linW, const float* __restrict__ linb,
    float* __restrict__ out, float* __restrict__ wsf)
{
    __shared__ float smem_f[12288];
    __shared__ int   smem_i[512];

    // ws layout (floats); h buffers are 4-k-packed [256][64][4]
    float* h0a = wsf;                 // 65536
    float* h0b = wsf + 65536;
    float* h1a = wsf + 131072;
    float* h1b = wsf + 196608;
    float* c0  = wsf + 262144;        // [1024][64]
    float* c1  = wsf + 327680;
    float* logits = wsf + 393216;     // [1024][64]
    int*   deint  = (int*)(wsf + 458752);   // [64]
    int*   gbar   = (int*)(wsf + 458816);   // barrier state (zeroed by memset)
    float* loss   = out + (size_t)TLz * Bz * Hz;

    // workspace (h/c/logits/deint/barrier) pre-zeroed by hipMemsetAsync.
    if (blockIdx.x == 0 && threadIdx.x == 0) *loss = 0.0f;

    int epoch = 0;

    float* h0c = h0a; float* h0n = h0b;
    float* h1c = h1a; float* h1n = h1b;

    // ---------------- encoder ----------------
    for (int t = 0; t < SLz; ++t) {
        lstm_phase<true>(smem_f, enc_embed, input_ids, SLz, t, nullptr, Ez,
                         eW0, eU0, eb0, h0c, h0n, c0);
        gsync(gbar, ++epoch);
        lstm_phase<false>(smem_f, nullptr, nullptr, 0, 0, h0n, Hz,
                          eW1, eU1, eb1, h1c, h1n, c1);
        gsync(gbar, ++epoch);
        float* tmp = h0c; h0c = h0n; h0n = tmp;
        tmp = h1c; h1c = h1n; h1n = tmp;
    }

    // ---------------- decoder ----------------
    for (int t = 0; t < TLz; ++t) {
        lstm_phase<true>(smem_f, dec_embed, deint, 1, 0, nullptr, Ez,
                         dW0, dU0, db0, h0c, h0n, c0);
        gsync(gbar, ++epoch);
        lstm_phase<false>(smem_f, nullptr, nullptr, 0, 0, h0n, Hz,
                          dW1, dU1, db1, h1c, h1n, c1);
        gsync(gbar, ++epoch);
        head_phase(smem_f, linW, linb, h1n, logits);
        gsync(gbar, ++epoch);
        softmax_phase(smem_f, smem_i, t, logits, tag_ids, out, deint, loss);
        gsync(gbar, ++epoch);
        float* tmp = h0c; h0c = h0n; h0n = tmp;
        tmp = h1c; h1c = h1n; h1n = tmp;
    }
}

extern "C" void kernel_launch(void* const* d_in, const int* in_sizes, int n_in,
                              void* d_out, int out_size, void* d_ws, size_t ws_size,
                              hipStream_t stream) {
    const int*   input_ids = (const int*)d_in[0];
    const int*   tag_ids   = (const int*)d_in[1];
    const float* enc_embed = (const float*)d_in[2];
    const float* eW0 = (const float*)d_in[3];
    const float* eU0 = (const float*)d_in[4];
    const float* eb0 = (const float*)d_in[5];
    const float* eW1 = (const float*)d_in[6];
    const float* eU1 = (const float*)d_in[7];
    const float* eb1 = (const float*)d_in[8];
    const float* dec_embed = (const float*)d_in[9];
    const float* dW0 = (const float*)d_in[10];
    const float* dU0 = (const float*)d_in[11];
    const float* db0 = (const float*)d_in[12];
    const float* dW1 = (const float*)d_in[13];
    const float* dU1 = (const float*)d_in[14];
    const float* db1 = (const float*)d_in[15];
    const float* linW = (const float*)d_in[16];
    const float* linb = (const float*)d_in[17];
    float* out = (float*)d_out;
    float* wsf = (float*)d_ws;

    // zero h/c/logits/deint + barrier state (stream-ordered, capture-safe)
    (void)hipMemsetAsync(d_ws, 0, (size_t)459136 * sizeof(float), stream);

    void* args[] = { &input_ids, &tag_ids, &enc_embed,
                     &eW0, &eU0, &eb0, &eW1, &eU1, &eb1,
                     &dec_embed, &dW0, &dU0, &db0, &dW1, &dU1, &db1,
                     &linW, &linb, &out, &wsf };
    (void)hipLaunchCooperativeKernel(seq2seq_kernel, dim3(NBLK), dim3(TPB),
                                     args, 0u, stream);
}